// Round 11
// baseline (199.415 us; speedup 1.0000x reference)
//
#include <hip/hip_runtime.h>

using u16 = unsigned short;
using short4v = __attribute__((ext_vector_type(4))) short;
using short8 = __attribute__((ext_vector_type(8))) short;
using floatx4 = __attribute__((ext_vector_type(4))) float;

__device__ __forceinline__ float bf2f(u16 h) {
  union { unsigned int u; float f; } v;
  v.u = ((unsigned int)h) << 16;
  return v.f;
}
__device__ __forceinline__ u16 f2bf(float f) {
  union { float f; unsigned int u; } v;
  v.f = f;
  unsigned int u = v.u;
  return (u16)((u + 0x7FFFu + ((u >> 16) & 1u)) >> 16);
}
__device__ __forceinline__ u16 f2bf_rtz(float f) {  // truncate: 1 op
  union { float f; unsigned int u; } v;
  v.f = f;
  return (u16)(v.u >> 16);
}

// raw v_exp_f32 / v_rcp_f32 (exp2f() lowers to the safe OCML sequence with
// range/denormal fixup; our |s|<=11.5 never needs it). Verified r7: -5µs attn.
__device__ __forceinline__ float exp2_raw(float x) {
  return __builtin_amdgcn_exp2f(x);
}
__device__ __forceinline__ float rcp_raw(float x) {
  return __builtin_amdgcn_rcpf(x);
}

// async global->LDS 16B copy (dest must be uniform base + lane*16)
typedef const __attribute__((address_space(1))) unsigned int* gas_t;
typedef __attribute__((address_space(3))) unsigned int* las_t;
__device__ __forceinline__ void gl_lds16(const u16* g, u16* l) {
  __builtin_amdgcn_global_load_lds((gas_t)(const void*)g, (las_t)(void*)l, 16,
                                   0, 0);
}

#define MFMA32 __builtin_amdgcn_mfma_f32_16x16x32_bf16

// Q prescale: 0.125 (hd^-0.5) * log2(e), so scores come out in log2 domain
#define QSCALE 0.180336880111f

// ---------------------------------------------------------------------------
// All f32 -> bf16 conversions in ONE launch.
// ---------------------------------------------------------------------------
__global__ __launch_bounds__(256) void cvt_all(
    const float* __restrict__ x, const float* __restrict__ wq,
    const float* __restrict__ wp, u16* __restrict__ xb, u16* __restrict__ wqb,
    u16* __restrict__ wpb) {
  int i = blockIdx.x * 256 + threadIdx.x;
  const float* src;
  u16* dst;
  int off;
  if (i < 1048576) {
    src = x; dst = xb; off = i;
  } else if (i < 1048576 + 786432) {
    src = wq; dst = wqb; off = i - 1048576;
  } else {
    src = wp; dst = wpb; off = i - 1835008;
  }
  float4 v = ((const float4*)src)[off];
  ushort4 o;
  o.x = f2bf(v.x);
  o.y = f2bf(v.y);
  o.z = f2bf(v.z);
  o.w = f2bf(v.w);
  ((ushort4*)dst)[off] = o;
}

// ---------------------------------------------------------------------------
// NT GEMM (r7 form, used for proj): C = A @ B^T, bf16 in, f32 acc. BK=64
// single-buffer (r8 dbuf regressed; residency TLP beats in-block prefetch).
// Both-sides XOR swizzle, bank conflicts measured 0.
// ---------------------------------------------------------------------------
template <int BIAS, int OUTBF16, int MT>
__global__ __launch_bounds__(256) void gemm_nt(
    const u16* __restrict__ A, const u16* __restrict__ B,
    const float* __restrict__ bias, void* __restrict__ Cout,
    int M, int N, int K) {
  constexpr int ROWS_A = MT * 32;
  __shared__ u16 As[ROWS_A * 64];
  __shared__ u16 Bs[128 * 64];
  const int tid = threadIdx.x;
  const int lane = tid & 63;
  const int wave = tid >> 6;
  const int col = lane & 15;
  const int quad = lane >> 4;
  const int bm = blockIdx.y * ROWS_A;
  const int bn = blockIdx.x * 128;
  const int wm = (wave >> 1) * (MT * 16);
  const int wn = (wave & 1) * 64;
  const int rsw = col & 7;  // == row&7 for every fragment row we read

  floatx4 acc[MT][4] = {};

  for (int kb = 0; kb < K; kb += 64) {
    __syncthreads();  // previous fragment reads done
#pragma unroll
    for (int c = tid; c < ROWS_A * 8; c += 256) {
      const int row = c >> 3, s = (c & 7) ^ (row & 7);
      gl_lds16(A + (size_t)(bm + row) * K + kb + s * 8, As + c * 8);
    }
#pragma unroll
    for (int c = tid; c < 1024; c += 256) {
      const int row = c >> 3, s = (c & 7) ^ (row & 7);
      gl_lds16(B + (size_t)(bn + row) * K + kb + s * 8, Bs + c * 8);
    }
    __syncthreads();  // fills visible

#pragma unroll
    for (int kk = 0; kk < 2; kk++) {
      short8 af[MT], bfr[4];
#pragma unroll
      for (int i = 0; i < MT; i++)
        af[i] = *(const short8*)(As + (wm + i * 16 + col) * 64 +
                                 ((kk * 4 + quad) ^ rsw) * 8);
#pragma unroll
      for (int i = 0; i < 4; i++)
        bfr[i] = *(const short8*)(Bs + (wn + i * 16 + col) * 64 +
                                  ((kk * 4 + quad) ^ rsw) * 8);
#pragma unroll
      for (int mi = 0; mi < MT; mi++)
#pragma unroll
        for (int ni = 0; ni < 4; ni++)
          acc[mi][ni] = MFMA32(af[mi], bfr[ni], acc[mi][ni], 0, 0, 0);
    }
  }

#pragma unroll
  for (int mi = 0; mi < MT; mi++) {
#pragma unroll
    for (int ni = 0; ni < 4; ni++) {
#pragma unroll
      for (int r = 0; r < 4; r++) {
        int row = bm + wm + mi * 16 + quad * 4 + r;
        int c = bn + wn + ni * 16 + col;
        float v = acc[mi][ni][r];
        if (BIAS) v += bias[c];
        if (OUTBF16)
          ((u16*)Cout)[(size_t)row * N + c] = f2bf(v);
        else
          ((float*)Cout)[(size_t)row * N + c] = v;
      }
    }
  }
}

// ---------------------------------------------------------------------------
// Fused qkv GEMM + RMSNorm + RoPE + V-transpose (r11). Replaces the old
// qkv gemm_nt + rope_v pair and deletes the 24MB qkv intermediate.
// Key geometry: wave tile = 64 features = EXACTLY one head-section.
//   c0 = bn+wn; type = c0>>10 (0=Q,1=K,2=V, BLOCK-uniform since 1024|128grid)
//   h = (c0>>6)&15 (wave-uniform); d = ni*16+col; token n from (mi,quad,r).
// Q/K epilogue: per (mi): ss[r] = sum_f acc^2 via 4 per-lane squares +
//   shfl_xor{1,2,4,8} over the 16-col group (full 64-dim head in-wave);
//   rsqrt -> normalize*w; RoPE partner = shfl_xor(.,1) (adjacent feature);
//   cos/sin from tables; QSCALE folded into Q; scalar u16 stores (32B runs).
// V epilogue: 4 r-consecutive tokens at fixed d pack into ONE b64 store
//   directly into Vt's [bh*64+d][n] transposed layout. No LDS needed.
// Main K-loop byte-identical to gemm_nt.
// ---------------------------------------------------------------------------
__global__ __launch_bounds__(256) void gemm_qkv(
    const u16* __restrict__ A, const u16* __restrict__ B,
    const float* __restrict__ qw, const float* __restrict__ kw,
    const float* __restrict__ pcos, const float* __restrict__ psin,
    u16* __restrict__ Qb, u16* __restrict__ Kb, u16* __restrict__ Vt) {
  constexpr int K = 1024;
  __shared__ u16 As[128 * 64];
  __shared__ u16 Bs[128 * 64];
  const int tid = threadIdx.x;
  const int lane = tid & 63;
  const int wave = tid >> 6;
  const int col = lane & 15;
  const int quad = lane >> 4;
  const int bm = blockIdx.y * 128;
  const int bn = blockIdx.x * 128;
  const int wm = (wave >> 1) * 64;
  const int wn = (wave & 1) * 64;
  const int rsw = col & 7;

  floatx4 acc[4][4] = {};

  for (int kb = 0; kb < K; kb += 64) {
    __syncthreads();
#pragma unroll
    for (int c = tid; c < 1024; c += 256) {
      const int row = c >> 3, s = (c & 7) ^ (row & 7);
      gl_lds16(A + (size_t)(bm + row) * K + kb + s * 8, As + c * 8);
    }
#pragma unroll
    for (int c = tid; c < 1024; c += 256) {
      const int row = c >> 3, s = (c & 7) ^ (row & 7);
      gl_lds16(B + (size_t)(bn + row) * K + kb + s * 8, Bs + c * 8);
    }
    __syncthreads();

#pragma unroll
    for (int kk = 0; kk < 2; kk++) {
      short8 af[4], bfr[4];
#pragma unroll
      for (int i = 0; i < 4; i++)
        af[i] = *(const short8*)(As + (wm + i * 16 + col) * 64 +
                                 ((kk * 4 + quad) ^ rsw) * 8);
#pragma unroll
      for (int i = 0; i < 4; i++)
        bfr[i] = *(const short8*)(Bs + (wn + i * 16 + col) * 64 +
                                  ((kk * 4 + quad) ^ rsw) * 8);
#pragma unroll
      for (int mi = 0; mi < 4; mi++)
#pragma unroll
        for (int ni = 0; ni < 4; ni++)
          acc[mi][ni] = MFMA32(af[mi], bfr[ni], acc[mi][ni], 0, 0, 0);
    }
  }

  // ---- fused epilogue
  const int c0 = bn + wn;          // wave's feature base in [0,3072)
  const int type = c0 >> 10;       // 0=Q, 1=K, 2=V (block-uniform)
  const int h = (c0 >> 6) & 15;    // head (wave-uniform)
  const int b = bm >> 11;          // batch
  const int bh = b * 16 + h;
  const int nt0 = (bm & 2047) + wm;  // token base; n = nt0+mi*16+quad*4+r

  if (type == 2) {
    // V: direct transposed b64 stores (4 consecutive tokens, fixed d)
#pragma unroll
    for (int mi = 0; mi < 4; mi++) {
#pragma unroll
      for (int ni = 0; ni < 4; ni++) {
        const int d = ni * 16 + col;
        const int n0 = nt0 + mi * 16 + quad * 4;
        short4v pk;
#pragma unroll
        for (int r = 0; r < 4; r++) pk[r] = (short)f2bf(acc[mi][ni][r]);
        *(short4v*)&Vt[((size_t)(bh * 64 + d)) * 2048 + n0] = pk;
      }
    }
  } else {
    u16* const dst = type ? Kb : Qb;
    const float* const nw = type ? kw : qw;
    float wloc[4];
#pragma unroll
    for (int ni = 0; ni < 4; ni++) wloc[ni] = nw[ni * 16 + col];

#pragma unroll
    for (int mi = 0; mi < 4; mi++) {
      // sum of squares over the 64-dim head for each of this lane's 4 rows
      floatx4 ss = {};
#pragma unroll
      for (int ni = 0; ni < 4; ni++)
#pragma unroll
        for (int r = 0; r < 4; r++) ss[r] += acc[mi][ni][r] * acc[mi][ni][r];
#pragma unroll
      for (int off = 1; off <= 8; off <<= 1)
#pragma unroll
        for (int r = 0; r < 4; r++) ss[r] += __shfl_xor(ss[r], off);
      floatx4 rn;
#pragma unroll
      for (int r = 0; r < 4; r++)
        rn[r] = rsqrtf(ss[r] * (1.0f / 64.0f) + 1e-6f);

#pragma unroll
      for (int ni = 0; ni < 4; ni++) {
        float nv[4], pv[4];
#pragma unroll
        for (int r = 0; r < 4; r++) nv[r] = acc[mi][ni][r] * rn[r] * wloc[ni];
#pragma unroll
        for (int r = 0; r < 4; r++) pv[r] = __shfl_xor(nv[r], 1);
#pragma unroll
        for (int r = 0; r < 4; r++) {
          const int n = nt0 + mi * 16 + quad * 4 + r;
          const float cc = pcos[n * 32 + ni * 8 + (col >> 1)];
          const float sn = psin[n * 32 + ni * 8 + (col >> 1)];
          float out = (col & 1) ? pv[r] * sn + nv[r] * cc
                                : nv[r] * cc - pv[r] * sn;
          if (type == 0) out *= QSCALE;
          dst[((size_t)(bh * 2048 + n)) * 64 + ni * 16 + col] = f2bf(out);
        }
      }
    }
  }
}

// ---------------------------------------------------------------------------
// Flash attention v17 (causal), unchanged from r10 (total-best 199.4µs):
// v11 structure + raw v_exp_f32/v_rcp_f32 + stride-64 granule-swizzled P
// (LDS 40960B).
// ---------------------------------------------------------------------------
__global__ __launch_bounds__(256) void attn_flash(
    const u16* __restrict__ Q, const u16* __restrict__ Kk,
    const u16* __restrict__ Vt, u16* __restrict__ O) {
  __shared__ u16 Ks[2][2][64 * 32];  // [buf][d-half][key][32d]
  __shared__ u16 Vs[2][2][64 * 32];  // [buf][key-half][d][32keys]
  __shared__ u16 Pb[4][16 * 64];     // per-wave P, [q][key], granule-swizzled
  const int id = blockIdx.x;
  const int bh = id & 31;
  const int tile = 31 - (id >> 5);  // big tiles dispatch first
  const int tid = threadIdx.x;
  const int lane = tid & 63;
  const int wave = tid >> 6;
  const int col = lane & 15;
  const int quad = lane >> 4;
  const int srow = tid >> 2;                      // staging: row 0..63
  const int sswz = ((tid & 3) ^ (srow & 3)) * 8;  // swizzled source piece
  const int rq = (quad ^ (col & 3)) * 8;          // matching fragment piece
  const int pswz = (col & 7) << 1;                // P granule XOR (even)

  const u16* Qh = Q + (size_t)bh * 2048 * 64;
  const u16* Kh = Kk + (size_t)bh * 2048 * 64;
  const u16* Vh = Vt + (size_t)bh * 64 * 2048;
  const int b = bh >> 4, h = bh & 15;

  const int q0 = tile * 64 + wave * 16;  // this wave's 16 q-rows

  short8 aq[2];
#pragma unroll
  for (int ks = 0; ks < 2; ks++)
    aq[ks] = *(const short8*)(Qh + (size_t)(q0 + col) * 64 + ks * 32 + quad * 8);

  short8 ones;
#pragma unroll
  for (int j = 0; j < 8; j++) ones[j] = (short)0x3F80;  // bf16 1.0

  floatx4 accO[4] = {};
  floatx4 lacc = {};  // row-sums via MFMA: lacc[r] = l(q0+quad*4+r)
  const int nsteps = tile + 1;

  // prologue: stage K,V tile 0 into buffer 0 (swizzled source pieces)
#pragma unroll
  for (int half = 0; half < 2; half++) {
    gl_lds16(Kh + (size_t)srow * 64 + half * 32 + sswz,
             &Ks[0][half][0] + tid * 8);
    gl_lds16(Vh + (size_t)srow * 2048 + half * 32 + sswz,
             &Vs[0][half][0] + tid * 8);
  }
  __syncthreads();

  int cur = 0;
  for (int kt = 0; kt < nsteps; kt++) {
    const int j0 = kt * 64;

    // prefetch next K,V tile into the other buffer — issued before all of
    // this step's compute; the end-of-step barrier drains it ~for free
    if (kt + 1 < nsteps) {
      const int j1 = j0 + 64;
#pragma unroll
      for (int half = 0; half < 2; half++) {
        gl_lds16(Kh + (size_t)(j1 + srow) * 64 + half * 32 + sswz,
                 &Ks[cur ^ 1][half][0] + tid * 8);
        gl_lds16(Vh + (size_t)srow * 2048 + j1 + half * 32 + sswz,
                 &Vs[cur ^ 1][half][0] + tid * 8);
      }
    }

    // S^T = K Q^T from the resident buffer:
    // s[nt][r] = S^T[key=j0+nt*16+quad*4+r][q=q0+col]
    floatx4 s[4] = {};
#pragma unroll
    for (int nt = 0; nt < 4; nt++) {
#pragma unroll
      for (int ks = 0; ks < 2; ks++) {
        short8 bk = *(const short8*)&Ks[cur][ks][(nt * 16 + col) * 32 + rq];
        s[nt] = MFMA32(bk, aq[ks], s[nt], 0, 0, 0);
      }
    }

    // p = exp2(s); mask only on diagonal step; packed b64 P write at the
    // granule-swizzled slot (granule g = nt*4+quad)
    if (j0 + 63 <= q0) {  // fully unmasked fast path
#pragma unroll
      for (int nt = 0; nt < 4; nt++) {
        short4v pk;
#pragma unroll
        for (int r = 0; r < 4; r++)
          pk[r] = (short)f2bf_rtz(exp2_raw(s[nt][r]));
        *(short4v*)&Pb[wave][col * 64 + ((nt * 4 + quad) ^ pswz) * 4] = pk;
      }
    } else {  // diagonal-adjacent: per-key causal mask
      const int qg = q0 + col;
#pragma unroll
      for (int nt = 0; nt < 4; nt++) {
        const int jgb = j0 + nt * 16 + quad * 4;
        short4v pk;
#pragma unroll
        for (int r = 0; r < 4; r++) {
          float pv = (jgb + r <= qg) ? exp2_raw(s[nt][r]) : 0.0f;
          pk[r] = (short)f2bf_rtz(pv);
        }
        *(short4v*)&Pb[wave][col * 64 + ((nt * 4 + quad) ^ pswz) * 4] = pk;
      }
    }
    // no barrier: Pb[wave] is wave-private, lgkmcnt orders write->read

    // b128 P reads: granule pair (kf*8+quad*2, +1); even XOR keeps the pair
    // adjacent and 16B-aligned
    short8 ap[2];
#pragma unroll
    for (int kf = 0; kf < 2; kf++)
      ap[kf] = *(const short8*)&Pb[wave][col * 64 +
                                         ((kf * 8 + quad * 2) ^ pswz) * 4];

    // row-sums via MFMA against ones (A-operand already loaded)
#pragma unroll
    for (int kf = 0; kf < 2; kf++)
      lacc = MFMA32(ap[kf], ones, lacc, 0, 0, 0);

#pragma unroll
    for (int nt = 0; nt < 4; nt++) {
#pragma unroll
      for (int kf = 0; kf < 2; kf++) {
        short8 bv = *(const short8*)&Vs[cur][kf][(nt * 16 + col) * 32 + rq];
        accO[nt] = MFMA32(ap[kf], bv, accO[nt], 0, 0, 0);
      }
    }

    __syncthreads();  // drains prefetch (vmcnt) + this step's LDS reads
    cur ^= 1;
  }

  float lrec[4];
#pragma unroll
  for (int r = 0; r < 4; r++) lrec[r] = rcp_raw(lacc[r]);

  // epilogue: O token-major [b][n][h][d] feeding the proj GEMM
#pragma unroll
  for (int nt = 0; nt < 4; nt++) {
#pragma unroll
    for (int r = 0; r < 4; r++) {
      int qg = q0 + quad * 4 + r;
      int d = nt * 16 + col;
      O[((size_t)(b * 2048 + qg) * 16 + h) * 64 + d] =
          f2bf(accO[nt][r] * lrec[r]);
    }
  }
}

// ---------------------------------------------------------------------------
extern "C" void kernel_launch(void* const* d_in, const int* in_sizes, int n_in,
                              void* d_out, int out_size, void* d_ws,
                              size_t ws_size, hipStream_t stream) {
  const float* x = (const float*)d_in[0];        // [2,2048,1024] f32
  const float* qkv_w = (const float*)d_in[1];    // [3072,1024] f32
  const float* q_norm_w = (const float*)d_in[2]; // [64] f32
  const float* k_norm_w = (const float*)d_in[3]; // [64] f32
  const float* proj_w = (const float*)d_in[4];   // [1024,1024] f32
  const float* proj_b = (const float*)d_in[5];   // [1024] f32
  const float* pos_cos = (const float*)d_in[6];  // [2048,32] f32
  const float* pos_sin = (const float*)d_in[7];  // [2048,32] f32
  // d_in[8] = causal mask: known analytically, ignored

  char* ws = (char*)d_ws;
  u16* xb = (u16*)ws;                          //  8 MB (4096*1024 bf16)
  u16* wqkvb = (u16*)(ws + 8388608);           //  6 MB (3072*1024 bf16)
  u16* wprojb = (u16*)(ws + 14680064);         //  2 MB (1024*1024 bf16)
  // (16..40 MB region free — the old qkv intermediate is deleted in r11)
  u16* Qb = (u16*)(ws + 41943040);             //  8 MB
  u16* Kb = (u16*)(ws + 50331648);             //  8 MB
  u16* Vt = (u16*)(ws + 58720256);             //  8 MB
  u16* AO = (u16*)(ws + 67108864);             //  8 MB  (total 72 MB)

  // 0) all f32 -> bf16 conversions, one launch
  cvt_all<<<8192, 256, 0, stream>>>(x, qkv_w, proj_w, xb, wqkvb, wprojb);

  // 1) fused qkv GEMM + RMSNorm + RoPE + V-transpose -> Qb, Kb, Vt directly
  gemm_qkv<<<dim3(24, 32), 256, 0, stream>>>(xb, wqkvb, q_norm_w, k_norm_w,
                                             pos_cos, pos_sin, Qb, Kb, Vt);

  // 2) causal flash attention v17 (unchanged)
  attn_flash<<<dim3(1024), 256, 0, stream>>>(Qb, Kb, Vt, AO);

  // 3) out = AO @ proj_w^T + proj_b: 64x128 tiles -> 512 blocks (2/CU), f32
  gemm_nt<1, 0, 2><<<dim3(8, 64), 256, 0, stream>>>(AO, wprojb, proj_b,
                                                    (float*)d_out, 4096, 1024,
                                                    1024);
}

// Round 12
// 197.018 us; speedup vs baseline: 1.0122x; 1.0122x over previous
//
#include <hip/hip_runtime.h>

using u16 = unsigned short;
using short4v = __attribute__((ext_vector_type(4))) short;
using short8 = __attribute__((ext_vector_type(8))) short;
using floatx4 = __attribute__((ext_vector_type(4))) float;

__device__ __forceinline__ float bf2f(u16 h) {
  union { unsigned int u; float f; } v;
  v.u = ((unsigned int)h) << 16;
  return v.f;
}
__device__ __forceinline__ u16 f2bf(float f) {
  union { float f; unsigned int u; } v;
  v.f = f;
  unsigned int u = v.u;
  return (u16)((u + 0x7FFFu + ((u >> 16) & 1u)) >> 16);
}
__device__ __forceinline__ u16 f2bf_rtz(float f) {  // truncate: 1 op
  union { float f; unsigned int u; } v;
  v.f = f;
  return (u16)(v.u >> 16);
}

// raw v_exp_f32 / v_rcp_f32 (exp2f() lowers to the safe OCML sequence with
// range/denormal fixup; our |s|<=11.5 never needs it). Verified r7: -5µs attn.
__device__ __forceinline__ float exp2_raw(float x) {
  return __builtin_amdgcn_exp2f(x);
}
__device__ __forceinline__ float rcp_raw(float x) {
  return __builtin_amdgcn_rcpf(x);
}

// async global->LDS 16B copy (dest must be uniform base + lane*16)
typedef const __attribute__((address_space(1))) unsigned int* gas_t;
typedef __attribute__((address_space(3))) unsigned int* las_t;
__device__ __forceinline__ void gl_lds16(const u16* g, u16* l) {
  __builtin_amdgcn_global_load_lds((gas_t)(const void*)g, (las_t)(void*)l, 16,
                                   0, 0);
}

#define MFMA32 __builtin_amdgcn_mfma_f32_16x16x32_bf16

// Q prescale: 0.125 (hd^-0.5) * log2(e), so scores come out in log2 domain
#define QSCALE 0.180336880111f

// ---------------------------------------------------------------------------
// All f32 -> bf16 conversions in ONE launch.
// ---------------------------------------------------------------------------
__global__ __launch_bounds__(256) void cvt_all(
    const float* __restrict__ x, const float* __restrict__ wq,
    const float* __restrict__ wp, u16* __restrict__ xb, u16* __restrict__ wqb,
    u16* __restrict__ wpb) {
  int i = blockIdx.x * 256 + threadIdx.x;
  const float* src;
  u16* dst;
  int off;
  if (i < 1048576) {
    src = x; dst = xb; off = i;
  } else if (i < 1048576 + 786432) {
    src = wq; dst = wqb; off = i - 1048576;
  } else {
    src = wp; dst = wpb; off = i - 1835008;
  }
  float4 v = ((const float4*)src)[off];
  ushort4 o;
  o.x = f2bf(v.x);
  o.y = f2bf(v.y);
  o.z = f2bf(v.z);
  o.w = f2bf(v.w);
  ((ushort4*)dst)[off] = o;
}

// ---------------------------------------------------------------------------
// NT GEMM (r7 form, used for proj): C = A @ B^T, bf16 in, f32 acc. BK=64
// single-buffer (r8 dbuf regressed; residency TLP beats in-block prefetch).
// Both-sides XOR swizzle, bank conflicts measured 0.
// ---------------------------------------------------------------------------
template <int BIAS, int OUTBF16, int MT>
__global__ __launch_bounds__(256) void gemm_nt(
    const u16* __restrict__ A, const u16* __restrict__ B,
    const float* __restrict__ bias, void* __restrict__ Cout,
    int M, int N, int K) {
  constexpr int ROWS_A = MT * 32;
  __shared__ u16 As[ROWS_A * 64];
  __shared__ u16 Bs[128 * 64];
  const int tid = threadIdx.x;
  const int lane = tid & 63;
  const int wave = tid >> 6;
  const int col = lane & 15;
  const int quad = lane >> 4;
  const int bm = blockIdx.y * ROWS_A;
  const int bn = blockIdx.x * 128;
  const int wm = (wave >> 1) * (MT * 16);
  const int wn = (wave & 1) * 64;
  const int rsw = col & 7;  // == row&7 for every fragment row we read

  floatx4 acc[MT][4] = {};

  for (int kb = 0; kb < K; kb += 64) {
    __syncthreads();  // previous fragment reads done
#pragma unroll
    for (int c = tid; c < ROWS_A * 8; c += 256) {
      const int row = c >> 3, s = (c & 7) ^ (row & 7);
      gl_lds16(A + (size_t)(bm + row) * K + kb + s * 8, As + c * 8);
    }
#pragma unroll
    for (int c = tid; c < 1024; c += 256) {
      const int row = c >> 3, s = (c & 7) ^ (row & 7);
      gl_lds16(B + (size_t)(bn + row) * K + kb + s * 8, Bs + c * 8);
    }
    __syncthreads();  // fills visible

#pragma unroll
    for (int kk = 0; kk < 2; kk++) {
      short8 af[MT], bfr[4];
#pragma unroll
      for (int i = 0; i < MT; i++)
        af[i] = *(const short8*)(As + (wm + i * 16 + col) * 64 +
                                 ((kk * 4 + quad) ^ rsw) * 8);
#pragma unroll
      for (int i = 0; i < 4; i++)
        bfr[i] = *(const short8*)(Bs + (wn + i * 16 + col) * 64 +
                                  ((kk * 4 + quad) ^ rsw) * 8);
#pragma unroll
      for (int mi = 0; mi < MT; mi++)
#pragma unroll
        for (int ni = 0; ni < 4; ni++)
          acc[mi][ni] = MFMA32(af[mi], bfr[ni], acc[mi][ni], 0, 0, 0);
    }
  }

#pragma unroll
  for (int mi = 0; mi < MT; mi++) {
#pragma unroll
    for (int ni = 0; ni < 4; ni++) {
#pragma unroll
      for (int r = 0; r < 4; r++) {
        int row = bm + wm + mi * 16 + quad * 4 + r;
        int c = bn + wn + ni * 16 + col;
        float v = acc[mi][ni][r];
        if (BIAS) v += bias[c];
        if (OUTBF16)
          ((u16*)Cout)[(size_t)row * N + c] = f2bf(v);
        else
          ((float*)Cout)[(size_t)row * N + c] = v;
      }
    }
  }
}

// ---------------------------------------------------------------------------
// Fused qkv GEMM + RMSNorm + RoPE + V-transpose (r12). r11 post-mortem:
// fused kernel = 51µs ~= the sum of its parts; cause = Q/K epilogue doing
// 64 SCALAR u16 global stores per lane (4x32B segments per wave-instr).
// r12 fix: after the K-loop, one __syncthreads turns As/Bs into scratch;
// each Q/K wave transposes its 64x64 output through a private LDS region
// (stride 80 u16: write pattern 2 lanes/bank, b128 read (8r+4c)%32 = 2-way,
// rows 16B-aligned), two 32-token halves (2560 u16 < 4096 u16/wave across
// As+Bs). Global stores become 8 x b128 per wave, each a dense 1KB segment.
// LDS write side = 64 cheap ds_write_b16. V path unchanged (b64 direct).
// Main K-loop byte-identical to gemm_nt.
// ---------------------------------------------------------------------------
__global__ __launch_bounds__(256) void gemm_qkv(
    const u16* __restrict__ A, const u16* __restrict__ B,
    const float* __restrict__ qw, const float* __restrict__ kw,
    const float* __restrict__ pcos, const float* __restrict__ psin,
    u16* __restrict__ Qb, u16* __restrict__ Kb, u16* __restrict__ Vt) {
  constexpr int K = 1024;
  __shared__ u16 As[128 * 64];
  __shared__ u16 Bs[128 * 64];
  const int tid = threadIdx.x;
  const int lane = tid & 63;
  const int wave = tid >> 6;
  const int col = lane & 15;
  const int quad = lane >> 4;
  const int bm = blockIdx.y * 128;
  const int bn = blockIdx.x * 128;
  const int wm = (wave >> 1) * 64;
  const int wn = (wave & 1) * 64;
  const int rsw = col & 7;

  floatx4 acc[4][4] = {};

  for (int kb = 0; kb < K; kb += 64) {
    __syncthreads();
#pragma unroll
    for (int c = tid; c < 1024; c += 256) {
      const int row = c >> 3, s = (c & 7) ^ (row & 7);
      gl_lds16(A + (size_t)(bm + row) * K + kb + s * 8, As + c * 8);
    }
#pragma unroll
    for (int c = tid; c < 1024; c += 256) {
      const int row = c >> 3, s = (c & 7) ^ (row & 7);
      gl_lds16(B + (size_t)(bn + row) * K + kb + s * 8, Bs + c * 8);
    }
    __syncthreads();

#pragma unroll
    for (int kk = 0; kk < 2; kk++) {
      short8 af[4], bfr[4];
#pragma unroll
      for (int i = 0; i < 4; i++)
        af[i] = *(const short8*)(As + (wm + i * 16 + col) * 64 +
                                 ((kk * 4 + quad) ^ rsw) * 8);
#pragma unroll
      for (int i = 0; i < 4; i++)
        bfr[i] = *(const short8*)(Bs + (wn + i * 16 + col) * 64 +
                                  ((kk * 4 + quad) ^ rsw) * 8);
#pragma unroll
      for (int mi = 0; mi < 4; mi++)
#pragma unroll
        for (int ni = 0; ni < 4; ni++)
          acc[mi][ni] = MFMA32(af[mi], bfr[ni], acc[mi][ni], 0, 0, 0);
    }
  }

  // ---- fused epilogue
  const int c0 = bn + wn;          // wave's feature base in [0,3072)
  const int type = c0 >> 10;       // 0=Q, 1=K, 2=V (block-uniform)
  const int h = (c0 >> 6) & 15;    // head (wave-uniform)
  const int b = bm >> 11;          // batch
  const int bh = b * 16 + h;
  const int nt0 = (bm & 2047) + wm;  // token base; n = nt0+mi*16+quad*4+r

  __syncthreads();  // all fragment reads done -> As/Bs become scratch

  if (type == 2) {
    // V: direct transposed b64 stores (4 consecutive tokens, fixed d)
#pragma unroll
    for (int mi = 0; mi < 4; mi++) {
#pragma unroll
      for (int ni = 0; ni < 4; ni++) {
        const int d = ni * 16 + col;
        const int n0 = nt0 + mi * 16 + quad * 4;
        short4v pk;
#pragma unroll
        for (int r = 0; r < 4; r++) pk[r] = (short)f2bf(acc[mi][ni][r]);
        *(short4v*)&Vt[((size_t)(bh * 64 + d)) * 2048 + n0] = pk;
      }
    }
  } else {
    // per-wave private transpose scratch: 4096 u16 each (As: waves 0,1;
    // Bs: waves 2,3); stride 80 u16 (160B, 16B-aligned, 2-way banks max)
    u16* const T = (wave < 2 ? As : Bs) + (wave & 1) * 4096;
    u16* const dst = type ? Kb : Qb;
    const float* const nw = type ? kw : qw;
    float wloc[4];
#pragma unroll
    for (int ni = 0; ni < 4; ni++) wloc[ni] = nw[ni * 16 + col];

#pragma unroll
    for (int mh = 0; mh < 2; mh++) {
#pragma unroll
      for (int mm = 0; mm < 2; mm++) {
        const int mi = mh * 2 + mm;
        // sum of squares over the 64-dim head for this lane's 4 rows
        floatx4 ss = {};
#pragma unroll
        for (int ni = 0; ni < 4; ni++)
#pragma unroll
          for (int r = 0; r < 4; r++)
            ss[r] += acc[mi][ni][r] * acc[mi][ni][r];
#pragma unroll
        for (int off = 1; off <= 8; off <<= 1)
#pragma unroll
          for (int r = 0; r < 4; r++) ss[r] += __shfl_xor(ss[r], off);
        floatx4 rn;
#pragma unroll
        for (int r = 0; r < 4; r++)
          rn[r] = rsqrtf(ss[r] * (1.0f / 64.0f) + 1e-6f);

#pragma unroll
        for (int ni = 0; ni < 4; ni++) {
          float nv[4], pv[4];
#pragma unroll
          for (int r = 0; r < 4; r++)
            nv[r] = acc[mi][ni][r] * rn[r] * wloc[ni];
#pragma unroll
          for (int r = 0; r < 4; r++) pv[r] = __shfl_xor(nv[r], 1);
#pragma unroll
          for (int r = 0; r < 4; r++) {
            const int n = nt0 + mi * 16 + quad * 4 + r;
            const float cc = pcos[n * 32 + ni * 8 + (col >> 1)];
            const float sn = psin[n * 32 + ni * 8 + (col >> 1)];
            float out = (col & 1) ? pv[r] * sn + nv[r] * cc
                                  : nv[r] * cc - pv[r] * sn;
            if (type == 0) out *= QSCALE;
            T[(mm * 16 + quad * 4 + r) * 80 + ni * 16 + col] = f2bf(out);
          }
        }
      }
      // read back transposed (wave-private; compiler orders via lgkmcnt)
      const int tl = lane >> 3;        // token row within group of 8
      const int dc = (lane & 7) * 8;   // 8-d chunk
#pragma unroll
      for (int i = 0; i < 4; i++) {
        short8 v = *(const short8*)&T[(i * 8 + tl) * 80 + dc];
        const int n = nt0 + mh * 32 + i * 8 + tl;
        *(short8*)&dst[((size_t)(bh * 2048 + n)) * 64 + dc] = v;
      }
    }
  }
}

// ---------------------------------------------------------------------------
// Flash attention v17 (causal), unchanged from r10 (total-best 199.4µs):
// v11 structure + raw v_exp_f32/v_rcp_f32 + stride-64 granule-swizzled P
// (LDS 40960B).
// ---------------------------------------------------------------------------
__global__ __launch_bounds__(256) void attn_flash(
    const u16* __restrict__ Q, const u16* __restrict__ Kk,
    const u16* __restrict__ Vt, u16* __restrict__ O) {
  __shared__ u16 Ks[2][2][64 * 32];  // [buf][d-half][key][32d]
  __shared__ u16 Vs[2][2][64 * 32];  // [buf][key-half][d][32keys]
  __shared__ u16 Pb[4][16 * 64];     // per-wave P, [q][key], granule-swizzled
  const int id = blockIdx.x;
  const int bh = id & 31;
  const int tile = 31 - (id >> 5);  // big tiles dispatch first
  const int tid = threadIdx.x;
  const int lane = tid & 63;
  const int wave = tid >> 6;
  const int col = lane & 15;
  const int quad = lane >> 4;
  const int srow = tid >> 2;                      // staging: row 0..63
  const int sswz = ((tid & 3) ^ (srow & 3)) * 8;  // swizzled source piece
  const int rq = (quad ^ (col & 3)) * 8;          // matching fragment piece
  const int pswz = (col & 7) << 1;                // P granule XOR (even)

  const u16* Qh = Q + (size_t)bh * 2048 * 64;
  const u16* Kh = Kk + (size_t)bh * 2048 * 64;
  const u16* Vh = Vt + (size_t)bh * 64 * 2048;
  const int b = bh >> 4, h = bh & 15;

  const int q0 = tile * 64 + wave * 16;  // this wave's 16 q-rows

  short8 aq[2];
#pragma unroll
  for (int ks = 0; ks < 2; ks++)
    aq[ks] = *(const short8*)(Qh + (size_t)(q0 + col) * 64 + ks * 32 + quad * 8);

  short8 ones;
#pragma unroll
  for (int j = 0; j < 8; j++) ones[j] = (short)0x3F80;  // bf16 1.0

  floatx4 accO[4] = {};
  floatx4 lacc = {};  // row-sums via MFMA: lacc[r] = l(q0+quad*4+r)
  const int nsteps = tile + 1;

  // prologue: stage K,V tile 0 into buffer 0 (swizzled source pieces)
#pragma unroll
  for (int half = 0; half < 2; half++) {
    gl_lds16(Kh + (size_t)srow * 64 + half * 32 + sswz,
             &Ks[0][half][0] + tid * 8);
    gl_lds16(Vh + (size_t)srow * 2048 + half * 32 + sswz,
             &Vs[0][half][0] + tid * 8);
  }
  __syncthreads();

  int cur = 0;
  for (int kt = 0; kt < nsteps; kt++) {
    const int j0 = kt * 64;

    // prefetch next K,V tile into the other buffer — issued before all of
    // this step's compute; the end-of-step barrier drains it ~for free
    if (kt + 1 < nsteps) {
      const int j1 = j0 + 64;
#pragma unroll
      for (int half = 0; half < 2; half++) {
        gl_lds16(Kh + (size_t)(j1 + srow) * 64 + half * 32 + sswz,
                 &Ks[cur ^ 1][half][0] + tid * 8);
        gl_lds16(Vh + (size_t)srow * 2048 + j1 + half * 32 + sswz,
                 &Vs[cur ^ 1][half][0] + tid * 8);
      }
    }

    // S^T = K Q^T from the resident buffer:
    // s[nt][r] = S^T[key=j0+nt*16+quad*4+r][q=q0+col]
    floatx4 s[4] = {};
#pragma unroll
    for (int nt = 0; nt < 4; nt++) {
#pragma unroll
      for (int ks = 0; ks < 2; ks++) {
        short8 bk = *(const short8*)&Ks[cur][ks][(nt * 16 + col) * 32 + rq];
        s[nt] = MFMA32(bk, aq[ks], s[nt], 0, 0, 0);
      }
    }

    // p = exp2(s); mask only on diagonal step; packed b64 P write at the
    // granule-swizzled slot (granule g = nt*4+quad)
    if (j0 + 63 <= q0) {  // fully unmasked fast path
#pragma unroll
      for (int nt = 0; nt < 4; nt++) {
        short4v pk;
#pragma unroll
        for (int r = 0; r < 4; r++)
          pk[r] = (short)f2bf_rtz(exp2_raw(s[nt][r]));
        *(short4v*)&Pb[wave][col * 64 + ((nt * 4 + quad) ^ pswz) * 4] = pk;
      }
    } else {  // diagonal-adjacent: per-key causal mask
      const int qg = q0 + col;
#pragma unroll
      for (int nt = 0; nt < 4; nt++) {
        const int jgb = j0 + nt * 16 + quad * 4;
        short4v pk;
#pragma unroll
        for (int r = 0; r < 4; r++) {
          float pv = (jgb + r <= qg) ? exp2_raw(s[nt][r]) : 0.0f;
          pk[r] = (short)f2bf_rtz(pv);
        }
        *(short4v*)&Pb[wave][col * 64 + ((nt * 4 + quad) ^ pswz) * 4] = pk;
      }
    }
    // no barrier: Pb[wave] is wave-private, lgkmcnt orders write->read

    // b128 P reads: granule pair (kf*8+quad*2, +1); even XOR keeps the pair
    // adjacent and 16B-aligned
    short8 ap[2];
#pragma unroll
    for (int kf = 0; kf < 2; kf++)
      ap[kf] = *(const short8*)&Pb[wave][col * 64 +
                                         ((kf * 8 + quad * 2) ^ pswz) * 4];

    // row-sums via MFMA against ones (A-operand already loaded)
#pragma unroll
    for (int kf = 0; kf < 2; kf++)
      lacc = MFMA32(ap[kf], ones, lacc, 0, 0, 0);

#pragma unroll
    for (int nt = 0; nt < 4; nt++) {
#pragma unroll
      for (int kf = 0; kf < 2; kf++) {
        short8 bv = *(const short8*)&Vs[cur][kf][(nt * 16 + col) * 32 + rq];
        accO[nt] = MFMA32(ap[kf], bv, accO[nt], 0, 0, 0);
      }
    }

    __syncthreads();  // drains prefetch (vmcnt) + this step's LDS reads
    cur ^= 1;
  }

  float lrec[4];
#pragma unroll
  for (int r = 0; r < 4; r++) lrec[r] = rcp_raw(lacc[r]);

  // epilogue: O token-major [b][n][h][d] feeding the proj GEMM
#pragma unroll
  for (int nt = 0; nt < 4; nt++) {
#pragma unroll
    for (int r = 0; r < 4; r++) {
      int qg = q0 + quad * 4 + r;
      int d = nt * 16 + col;
      O[((size_t)(b * 2048 + qg) * 16 + h) * 64 + d] =
          f2bf(accO[nt][r] * lrec[r]);
    }
  }
}

// ---------------------------------------------------------------------------
extern "C" void kernel_launch(void* const* d_in, const int* in_sizes, int n_in,
                              void* d_out, int out_size, void* d_ws,
                              size_t ws_size, hipStream_t stream) {
  const float* x = (const float*)d_in[0];        // [2,2048,1024] f32
  const float* qkv_w = (const float*)d_in[1];    // [3072,1024] f32
  const float* q_norm_w = (const float*)d_in[2]; // [64] f32
  const float* k_norm_w = (const float*)d_in[3]; // [64] f32
  const float* proj_w = (const float*)d_in[4];   // [1024,1024] f32
  const float* proj_b = (const float*)d_in[5];   // [1024] f32
  const float* pos_cos = (const float*)d_in[6];  // [2048,32] f32
  const float* pos_sin = (const float*)d_in[7];  // [2048,32] f32
  // d_in[8] = causal mask: known analytically, ignored

  char* ws = (char*)d_ws;
  u16* xb = (u16*)ws;                          //  8 MB (4096*1024 bf16)
  u16* wqkvb = (u16*)(ws + 8388608);           //  6 MB (3072*1024 bf16)
  u16* wprojb = (u16*)(ws + 14680064);         //  2 MB (1024*1024 bf16)
  // (16..40 MB region free — the qkv intermediate was deleted in r11)
  u16* Qb = (u16*)(ws + 41943040);             //  8 MB
  u16* Kb = (u16*)(ws + 50331648);             //  8 MB
  u16* Vt = (u16*)(ws + 58720256);             //  8 MB
  u16* AO = (u16*)(ws + 67108864);             //  8 MB  (total 72 MB)

  // 0) all f32 -> bf16 conversions, one launch
  cvt_all<<<8192, 256, 0, stream>>>(x, qkv_w, proj_w, xb, wqkvb, wprojb);

  // 1) fused qkv GEMM + RMSNorm + RoPE + V-transpose -> Qb, Kb, Vt directly
  gemm_qkv<<<dim3(24, 32), 256, 0, stream>>>(xb, wqkvb, q_norm_w, k_norm_w,
                                             pos_cos, pos_sin, Qb, Kb, Vt);

  // 2) causal flash attention v17 (unchanged)
  attn_flash<<<dim3(1024), 256, 0, stream>>>(Qb, Kb, Vt, AO);

  // 3) out = AO @ proj_w^T + proj_b: 64x128 tiles -> 512 blocks (2/CU), f32
  gemm_nt<1, 0, 2><<<dim3(8, 64), 256, 0, stream>>>(AO, wprojb, proj_b,
                                                    (float*)d_out, 4096, 1024,
                                                    1024);
}

// Round 13
// 196.772 us; speedup vs baseline: 1.0134x; 1.0012x over previous
//
#include <hip/hip_runtime.h>

using u16 = unsigned short;
using short4v = __attribute__((ext_vector_type(4))) short;
using short8 = __attribute__((ext_vector_type(8))) short;
using floatx4 = __attribute__((ext_vector_type(4))) float;

__device__ __forceinline__ float bf2f(u16 h) {
  union { unsigned int u; float f; } v;
  v.u = ((unsigned int)h) << 16;
  return v.f;
}
__device__ __forceinline__ u16 f2bf(float f) {
  union { float f; unsigned int u; } v;
  v.f = f;
  unsigned int u = v.u;
  return (u16)((u + 0x7FFFu + ((u >> 16) & 1u)) >> 16);
}
__device__ __forceinline__ u16 f2bf_rtz(float f) {  // truncate: 1 op
  union { float f; unsigned int u; } v;
  v.f = f;
  return (u16)(v.u >> 16);
}

// raw v_exp_f32 / v_rcp_f32 (exp2f() lowers to the safe OCML sequence with
// range/denormal fixup; our |s|<=11.5 never needs it). Verified r7: -5µs attn.
__device__ __forceinline__ float exp2_raw(float x) {
  return __builtin_amdgcn_exp2f(x);
}
__device__ __forceinline__ float rcp_raw(float x) {
  return __builtin_amdgcn_rcpf(x);
}

// async global->LDS 16B copy (dest must be uniform base + lane*16)
typedef const __attribute__((address_space(1))) unsigned int* gas_t;
typedef __attribute__((address_space(3))) unsigned int* las_t;
__device__ __forceinline__ void gl_lds16(const u16* g, u16* l) {
  __builtin_amdgcn_global_load_lds((gas_t)(const void*)g, (las_t)(void*)l, 16,
                                   0, 0);
}

#define MFMA32 __builtin_amdgcn_mfma_f32_16x16x32_bf16

// Q prescale: 0.125 (hd^-0.5) * log2(e), so scores come out in log2 domain
#define QSCALE 0.180336880111f

// ---------------------------------------------------------------------------
// All f32 -> bf16 conversions in ONE launch.
// ---------------------------------------------------------------------------
__global__ __launch_bounds__(256) void cvt_all(
    const float* __restrict__ x, const float* __restrict__ wq,
    const float* __restrict__ wp, u16* __restrict__ xb, u16* __restrict__ wqb,
    u16* __restrict__ wpb) {
  int i = blockIdx.x * 256 + threadIdx.x;
  const float* src;
  u16* dst;
  int off;
  if (i < 1048576) {
    src = x; dst = xb; off = i;
  } else if (i < 1048576 + 786432) {
    src = wq; dst = wqb; off = i - 1048576;
  } else {
    src = wp; dst = wpb; off = i - 1835008;
  }
  float4 v = ((const float4*)src)[off];
  ushort4 o;
  o.x = f2bf(v.x);
  o.y = f2bf(v.y);
  o.z = f2bf(v.z);
  o.w = f2bf(v.w);
  ((ushort4*)dst)[off] = o;
}

// ---------------------------------------------------------------------------
// NT GEMM (r7 form, used for proj): C = A @ B^T, bf16 in, f32 acc. BK=64
// single-buffer (r8 dbuf regressed; residency TLP beats in-block prefetch).
// Both-sides XOR swizzle, bank conflicts measured 0.
// r13: proj instantiated at MT=1 (32x128 tile) -> grid 1024 blocks = 4/CU
// residency (was MT=2, 512 blocks, 2/CU). r8/r9 showed cross-block TLP is
// what hides this structure's stage latency; proj was the last 2/CU kernel.
// Extra A/B reuse-amplification stays in L2/L3 (AO 8MB, proj_w 2MB).
// ---------------------------------------------------------------------------
template <int BIAS, int OUTBF16, int MT>
__global__ __launch_bounds__(256) void gemm_nt(
    const u16* __restrict__ A, const u16* __restrict__ B,
    const float* __restrict__ bias, void* __restrict__ Cout,
    int M, int N, int K) {
  constexpr int ROWS_A = MT * 32;
  __shared__ u16 As[ROWS_A * 64];
  __shared__ u16 Bs[128 * 64];
  const int tid = threadIdx.x;
  const int lane = tid & 63;
  const int wave = tid >> 6;
  const int col = lane & 15;
  const int quad = lane >> 4;
  const int bm = blockIdx.y * ROWS_A;
  const int bn = blockIdx.x * 128;
  const int wm = (wave >> 1) * (MT * 16);
  const int wn = (wave & 1) * 64;
  const int rsw = col & 7;  // == row&7 for every fragment row we read

  floatx4 acc[MT][4] = {};

  for (int kb = 0; kb < K; kb += 64) {
    __syncthreads();  // previous fragment reads done
#pragma unroll
    for (int c = tid; c < ROWS_A * 8; c += 256) {
      const int row = c >> 3, s = (c & 7) ^ (row & 7);
      gl_lds16(A + (size_t)(bm + row) * K + kb + s * 8, As + c * 8);
    }
#pragma unroll
    for (int c = tid; c < 1024; c += 256) {
      const int row = c >> 3, s = (c & 7) ^ (row & 7);
      gl_lds16(B + (size_t)(bn + row) * K + kb + s * 8, Bs + c * 8);
    }
    __syncthreads();  // fills visible

#pragma unroll
    for (int kk = 0; kk < 2; kk++) {
      short8 af[MT], bfr[4];
#pragma unroll
      for (int i = 0; i < MT; i++)
        af[i] = *(const short8*)(As + (wm + i * 16 + col) * 64 +
                                 ((kk * 4 + quad) ^ rsw) * 8);
#pragma unroll
      for (int i = 0; i < 4; i++)
        bfr[i] = *(const short8*)(Bs + (wn + i * 16 + col) * 64 +
                                  ((kk * 4 + quad) ^ rsw) * 8);
#pragma unroll
      for (int mi = 0; mi < MT; mi++)
#pragma unroll
        for (int ni = 0; ni < 4; ni++)
          acc[mi][ni] = MFMA32(af[mi], bfr[ni], acc[mi][ni], 0, 0, 0);
    }
  }

#pragma unroll
  for (int mi = 0; mi < MT; mi++) {
#pragma unroll
    for (int ni = 0; ni < 4; ni++) {
#pragma unroll
      for (int r = 0; r < 4; r++) {
        int row = bm + wm + mi * 16 + quad * 4 + r;
        int c = bn + wn + ni * 16 + col;
        float v = acc[mi][ni][r];
        if (BIAS) v += bias[c];
        if (OUTBF16)
          ((u16*)Cout)[(size_t)row * N + c] = f2bf(v);
        else
          ((float*)Cout)[(size_t)row * N + c] = v;
      }
    }
  }
}

// ---------------------------------------------------------------------------
// Fused qkv GEMM + RMSNorm + RoPE + V-transpose (r12 form, kept: 49.5µs).
// Main K-loop identical to gemm_nt; epilogue transposes Q/K through the
// dead As/Bs LDS (stride 80) for b128 dense stores; V stored b64 direct.
// ---------------------------------------------------------------------------
__global__ __launch_bounds__(256) void gemm_qkv(
    const u16* __restrict__ A, const u16* __restrict__ B,
    const float* __restrict__ qw, const float* __restrict__ kw,
    const float* __restrict__ pcos, const float* __restrict__ psin,
    u16* __restrict__ Qb, u16* __restrict__ Kb, u16* __restrict__ Vt) {
  constexpr int K = 1024;
  __shared__ u16 As[128 * 64];
  __shared__ u16 Bs[128 * 64];
  const int tid = threadIdx.x;
  const int lane = tid & 63;
  const int wave = tid >> 6;
  const int col = lane & 15;
  const int quad = lane >> 4;
  const int bm = blockIdx.y * 128;
  const int bn = blockIdx.x * 128;
  const int wm = (wave >> 1) * 64;
  const int wn = (wave & 1) * 64;
  const int rsw = col & 7;

  floatx4 acc[4][4] = {};

  for (int kb = 0; kb < K; kb += 64) {
    __syncthreads();
#pragma unroll
    for (int c = tid; c < 1024; c += 256) {
      const int row = c >> 3, s = (c & 7) ^ (row & 7);
      gl_lds16(A + (size_t)(bm + row) * K + kb + s * 8, As + c * 8);
    }
#pragma unroll
    for (int c = tid; c < 1024; c += 256) {
      const int row = c >> 3, s = (c & 7) ^ (row & 7);
      gl_lds16(B + (size_t)(bn + row) * K + kb + s * 8, Bs + c * 8);
    }
    __syncthreads();

#pragma unroll
    for (int kk = 0; kk < 2; kk++) {
      short8 af[4], bfr[4];
#pragma unroll
      for (int i = 0; i < 4; i++)
        af[i] = *(const short8*)(As + (wm + i * 16 + col) * 64 +
                                 ((kk * 4 + quad) ^ rsw) * 8);
#pragma unroll
      for (int i = 0; i < 4; i++)
        bfr[i] = *(const short8*)(Bs + (wn + i * 16 + col) * 64 +
                                  ((kk * 4 + quad) ^ rsw) * 8);
#pragma unroll
      for (int mi = 0; mi < 4; mi++)
#pragma unroll
        for (int ni = 0; ni < 4; ni++)
          acc[mi][ni] = MFMA32(af[mi], bfr[ni], acc[mi][ni], 0, 0, 0);
    }
  }

  // ---- fused epilogue
  const int c0 = bn + wn;          // wave's feature base in [0,3072)
  const int type = c0 >> 10;       // 0=Q, 1=K, 2=V (block-uniform)
  const int h = (c0 >> 6) & 15;    // head (wave-uniform)
  const int b = bm >> 11;          // batch
  const int bh = b * 16 + h;
  const int nt0 = (bm & 2047) + wm;  // token base; n = nt0+mi*16+quad*4+r

  __syncthreads();  // all fragment reads done -> As/Bs become scratch

  if (type == 2) {
    // V: direct transposed b64 stores (4 consecutive tokens, fixed d)
#pragma unroll
    for (int mi = 0; mi < 4; mi++) {
#pragma unroll
      for (int ni = 0; ni < 4; ni++) {
        const int d = ni * 16 + col;
        const int n0 = nt0 + mi * 16 + quad * 4;
        short4v pk;
#pragma unroll
        for (int r = 0; r < 4; r++) pk[r] = (short)f2bf(acc[mi][ni][r]);
        *(short4v*)&Vt[((size_t)(bh * 64 + d)) * 2048 + n0] = pk;
      }
    }
  } else {
    // per-wave private transpose scratch: 4096 u16 each (As: waves 0,1;
    // Bs: waves 2,3); stride 80 u16 (160B, 16B-aligned, 2-way banks max)
    u16* const T = (wave < 2 ? As : Bs) + (wave & 1) * 4096;
    u16* const dst = type ? Kb : Qb;
    const float* const nw = type ? kw : qw;
    float wloc[4];
#pragma unroll
    for (int ni = 0; ni < 4; ni++) wloc[ni] = nw[ni * 16 + col];

#pragma unroll
    for (int mh = 0; mh < 2; mh++) {
#pragma unroll
      for (int mm = 0; mm < 2; mm++) {
        const int mi = mh * 2 + mm;
        // sum of squares over the 64-dim head for this lane's 4 rows
        floatx4 ss = {};
#pragma unroll
        for (int ni = 0; ni < 4; ni++)
#pragma unroll
          for (int r = 0; r < 4; r++)
            ss[r] += acc[mi][ni][r] * acc[mi][ni][r];
#pragma unroll
        for (int off = 1; off <= 8; off <<= 1)
#pragma unroll
          for (int r = 0; r < 4; r++) ss[r] += __shfl_xor(ss[r], off);
        floatx4 rn;
#pragma unroll
        for (int r = 0; r < 4; r++)
          rn[r] = rsqrtf(ss[r] * (1.0f / 64.0f) + 1e-6f);

#pragma unroll
        for (int ni = 0; ni < 4; ni++) {
          float nv[4], pv[4];
#pragma unroll
          for (int r = 0; r < 4; r++)
            nv[r] = acc[mi][ni][r] * rn[r] * wloc[ni];
#pragma unroll
          for (int r = 0; r < 4; r++) pv[r] = __shfl_xor(nv[r], 1);
#pragma unroll
          for (int r = 0; r < 4; r++) {
            const int n = nt0 + mi * 16 + quad * 4 + r;
            const float cc = pcos[n * 32 + ni * 8 + (col >> 1)];
            const float sn = psin[n * 32 + ni * 8 + (col >> 1)];
            float out = (col & 1) ? pv[r] * sn + nv[r] * cc
                                  : nv[r] * cc - pv[r] * sn;
            if (type == 0) out *= QSCALE;
            T[(mm * 16 + quad * 4 + r) * 80 + ni * 16 + col] = f2bf(out);
          }
        }
      }
      // read back transposed (wave-private; compiler orders via lgkmcnt)
      const int tl = lane >> 3;        // token row within group of 8
      const int dc = (lane & 7) * 8;   // 8-d chunk
#pragma unroll
      for (int i = 0; i < 4; i++) {
        short8 v = *(const short8*)&T[(i * 8 + tl) * 80 + dc];
        const int n = nt0 + mh * 32 + i * 8 + tl;
        *(short8*)&dst[((size_t)(bh * 2048 + n)) * 64 + dc] = v;
      }
    }
  }
}

// ---------------------------------------------------------------------------
// Flash attention v17 (causal), unchanged from r10 (total-best):
// v11 structure + raw v_exp_f32/v_rcp_f32 + stride-64 granule-swizzled P
// (LDS 40960B).
// ---------------------------------------------------------------------------
__global__ __launch_bounds__(256) void attn_flash(
    const u16* __restrict__ Q, const u16* __restrict__ Kk,
    const u16* __restrict__ Vt, u16* __restrict__ O) {
  __shared__ u16 Ks[2][2][64 * 32];  // [buf][d-half][key][32d]
  __shared__ u16 Vs[2][2][64 * 32];  // [buf][key-half][d][32keys]
  __shared__ u16 Pb[4][16 * 64];     // per-wave P, [q][key], granule-swizzled
  const int id = blockIdx.x;
  const int bh = id & 31;
  const int tile = 31 - (id >> 5);  // big tiles dispatch first
  const int tid = threadIdx.x;
  const int lane = tid & 63;
  const int wave = tid >> 6;
  const int col = lane & 15;
  const int quad = lane >> 4;
  const int srow = tid >> 2;                      // staging: row 0..63
  const int sswz = ((tid & 3) ^ (srow & 3)) * 8;  // swizzled source piece
  const int rq = (quad ^ (col & 3)) * 8;          // matching fragment piece
  const int pswz = (col & 7) << 1;                // P granule XOR (even)

  const u16* Qh = Q + (size_t)bh * 2048 * 64;
  const u16* Kh = Kk + (size_t)bh * 2048 * 64;
  const u16* Vh = Vt + (size_t)bh * 64 * 2048;
  const int b = bh >> 4, h = bh & 15;

  const int q0 = tile * 64 + wave * 16;  // this wave's 16 q-rows

  short8 aq[2];
#pragma unroll
  for (int ks = 0; ks < 2; ks++)
    aq[ks] = *(const short8*)(Qh + (size_t)(q0 + col) * 64 + ks * 32 + quad * 8);

  short8 ones;
#pragma unroll
  for (int j = 0; j < 8; j++) ones[j] = (short)0x3F80;  // bf16 1.0

  floatx4 accO[4] = {};
  floatx4 lacc = {};  // row-sums via MFMA: lacc[r] = l(q0+quad*4+r)
  const int nsteps = tile + 1;

  // prologue: stage K,V tile 0 into buffer 0 (swizzled source pieces)
#pragma unroll
  for (int half = 0; half < 2; half++) {
    gl_lds16(Kh + (size_t)srow * 64 + half * 32 + sswz,
             &Ks[0][half][0] + tid * 8);
    gl_lds16(Vh + (size_t)srow * 2048 + half * 32 + sswz,
             &Vs[0][half][0] + tid * 8);
  }
  __syncthreads();

  int cur = 0;
  for (int kt = 0; kt < nsteps; kt++) {
    const int j0 = kt * 64;

    // prefetch next K,V tile into the other buffer — issued before all of
    // this step's compute; the end-of-step barrier drains it ~for free
    if (kt + 1 < nsteps) {
      const int j1 = j0 + 64;
#pragma unroll
      for (int half = 0; half < 2; half++) {
        gl_lds16(Kh + (size_t)(j1 + srow) * 64 + half * 32 + sswz,
                 &Ks[cur ^ 1][half][0] + tid * 8);
        gl_lds16(Vh + (size_t)srow * 2048 + j1 + half * 32 + sswz,
                 &Vs[cur ^ 1][half][0] + tid * 8);
      }
    }

    // S^T = K Q^T from the resident buffer:
    // s[nt][r] = S^T[key=j0+nt*16+quad*4+r][q=q0+col]
    floatx4 s[4] = {};
#pragma unroll
    for (int nt = 0; nt < 4; nt++) {
#pragma unroll
      for (int ks = 0; ks < 2; ks++) {
        short8 bk = *(const short8*)&Ks[cur][ks][(nt * 16 + col) * 32 + rq];
        s[nt] = MFMA32(bk, aq[ks], s[nt], 0, 0, 0);
      }
    }

    // p = exp2(s); mask only on diagonal step; packed b64 P write at the
    // granule-swizzled slot (granule g = nt*4+quad)
    if (j0 + 63 <= q0) {  // fully unmasked fast path
#pragma unroll
      for (int nt = 0; nt < 4; nt++) {
        short4v pk;
#pragma unroll
        for (int r = 0; r < 4; r++)
          pk[r] = (short)f2bf_rtz(exp2_raw(s[nt][r]));
        *(short4v*)&Pb[wave][col * 64 + ((nt * 4 + quad) ^ pswz) * 4] = pk;
      }
    } else {  // diagonal-adjacent: per-key causal mask
      const int qg = q0 + col;
#pragma unroll
      for (int nt = 0; nt < 4; nt++) {
        const int jgb = j0 + nt * 16 + quad * 4;
        short4v pk;
#pragma unroll
        for (int r = 0; r < 4; r++) {
          float pv = (jgb + r <= qg) ? exp2_raw(s[nt][r]) : 0.0f;
          pk[r] = (short)f2bf_rtz(pv);
        }
        *(short4v*)&Pb[wave][col * 64 + ((nt * 4 + quad) ^ pswz) * 4] = pk;
      }
    }
    // no barrier: Pb[wave] is wave-private, lgkmcnt orders write->read

    // b128 P reads: granule pair (kf*8+quad*2, +1); even XOR keeps the pair
    // adjacent and 16B-aligned
    short8 ap[2];
#pragma unroll
    for (int kf = 0; kf < 2; kf++)
      ap[kf] = *(const short8*)&Pb[wave][col * 64 +
                                         ((kf * 8 + quad * 2) ^ pswz) * 4];

    // row-sums via MFMA against ones (A-operand already loaded)
#pragma unroll
    for (int kf = 0; kf < 2; kf++)
      lacc = MFMA32(ap[kf], ones, lacc, 0, 0, 0);

#pragma unroll
    for (int nt = 0; nt < 4; nt++) {
#pragma unroll
      for (int kf = 0; kf < 2; kf++) {
        short8 bv = *(const short8*)&Vs[cur][kf][(nt * 16 + col) * 32 + rq];
        accO[nt] = MFMA32(ap[kf], bv, accO[nt], 0, 0, 0);
      }
    }

    __syncthreads();  // drains prefetch (vmcnt) + this step's LDS reads
    cur ^= 1;
  }

  float lrec[4];
#pragma unroll
  for (int r = 0; r < 4; r++) lrec[r] = rcp_raw(lacc[r]);

  // epilogue: O token-major [b][n][h][d] feeding the proj GEMM
#pragma unroll
  for (int nt = 0; nt < 4; nt++) {
#pragma unroll
    for (int r = 0; r < 4; r++) {
      int qg = q0 + quad * 4 + r;
      int d = nt * 16 + col;
      O[((size_t)(b * 2048 + qg) * 16 + h) * 64 + d] =
          f2bf(accO[nt][r] * lrec[r]);
    }
  }
}

// ---------------------------------------------------------------------------
extern "C" void kernel_launch(void* const* d_in, const int* in_sizes, int n_in,
                              void* d_out, int out_size, void* d_ws,
                              size_t ws_size, hipStream_t stream) {
  const float* x = (const float*)d_in[0];        // [2,2048,1024] f32
  const float* qkv_w = (const float*)d_in[1];    // [3072,1024] f32
  const float* q_norm_w = (const float*)d_in[2]; // [64] f32
  const float* k_norm_w = (const float*)d_in[3]; // [64] f32
  const float* proj_w = (const float*)d_in[4];   // [1024,1024] f32
  const float* proj_b = (const float*)d_in[5];   // [1024] f32
  const float* pos_cos = (const float*)d_in[6];  // [2048,32] f32
  const float* pos_sin = (const float*)d_in[7];  // [2048,32] f32
  // d_in[8] = causal mask: known analytically, ignored

  char* ws = (char*)d_ws;
  u16* xb = (u16*)ws;                          //  8 MB (4096*1024 bf16)
  u16* wqkvb = (u16*)(ws + 8388608);           //  6 MB (3072*1024 bf16)
  u16* wprojb = (u16*)(ws + 14680064);         //  2 MB (1024*1024 bf16)
  // (16..40 MB region free — the qkv intermediate was deleted in r11)
  u16* Qb = (u16*)(ws + 41943040);             //  8 MB
  u16* Kb = (u16*)(ws + 50331648);             //  8 MB
  u16* Vt = (u16*)(ws + 58720256);             //  8 MB
  u16* AO = (u16*)(ws + 67108864);             //  8 MB  (total 72 MB)

  // 0) all f32 -> bf16 conversions, one launch
  cvt_all<<<8192, 256, 0, stream>>>(x, qkv_w, proj_w, xb, wqkvb, wprojb);

  // 1) fused qkv GEMM + RMSNorm + RoPE + V-transpose -> Qb, Kb, Vt directly
  gemm_qkv<<<dim3(24, 32), 256, 0, stream>>>(xb, wqkvb, q_norm_w, k_norm_w,
                                             pos_cos, pos_sin, Qb, Kb, Vt);

  // 2) causal flash attention v17 (unchanged)
  attn_flash<<<dim3(1024), 256, 0, stream>>>(Qb, Kb, Vt, AO);

  // 3) out = AO @ proj_w^T + proj_b: 32x128 tiles -> 1024 blocks (4/CU), f32
  gemm_nt<1, 0, 1><<<dim3(8, 128), 256, 0, stream>>>(AO, wprojb, proj_b,
                                                     (float*)d_out, 4096, 1024,
                                                     1024);
}